// Round 1
// baseline (121.352 us; speedup 1.0000x reference)
//
#include <hip/hip_runtime.h>

// CreateInstMap: per-pixel argmin over K=64 centers of euclidean distance.
//   out[r,c] = 1 + argmin_k sqrt((px-cx[k])^2 + (py-cy[k])^2)
//   px = (c+1) - reg[0,r,c], py = (r+1) - reg[1,r,c]
//   cy[k] = cc[k,0], cx[k] = cc[k,1]   (note the reference swaps columns)
// xy_coords input (d_in[2]) is a deterministic meshgrid -> regenerated here.
//
// Exactness: numpy argmin ties -> first index. We replicate the reference's
// rounding bit-exactly: __fmul_rn/__fadd_rn (no FMA contraction) and
// __fsqrt_rn (correctly rounded, = np.sqrt), strict '<' update so the first
// minimum wins. This makes the output bit-identical to the reference.

#define H_ 1024
#define W_ 2048
#define K_ 64

__global__ __launch_bounds__(256) void inst_map_kernel(
    const float* __restrict__ reg,   // (2, H, W) float32
    const float* __restrict__ cc,    // (K, 2)   float32, [k] = (cy, cx)
    int* __restrict__ out)           // (H, W)   int32
{
    const int t    = blockIdx.x * 256 + threadIdx.x;
    const int base = t << 2;                  // 4 pixels per thread, same row (W%4==0)
    const int row  = base >> 11;              // base / W_
    const int col  = base & (W_ - 1);         // base % W_

    const float4 rx = *reinterpret_cast<const float4*>(reg + base);
    const float4 ry = *reinterpret_cast<const float4*>(reg + (H_ * W_) + base);

    const float yf = (float)(row + 1);
    float px[4], py[4];
    px[0] = (float)(col + 1) - rx.x;
    px[1] = (float)(col + 2) - rx.y;
    px[2] = (float)(col + 3) - rx.z;
    px[3] = (float)(col + 4) - rx.w;
    py[0] = yf - ry.x;
    py[1] = yf - ry.y;
    py[2] = yf - ry.z;
    py[3] = yf - ry.w;

    float sbest[4] = {INFINITY, INFINITY, INFINITY, INFINITY};
    int   bidx[4]  = {1, 1, 1, 1};

    #pragma unroll
    for (int k = 0; k < K_; ++k) {
        // uniform address -> scalar loads (s_load), off the VALU issue path
        const float cy = cc[2 * k];
        const float cx = cc[2 * k + 1];
        #pragma unroll
        for (int i = 0; i < 4; ++i) {
            const float dx = px[i] - cx;
            const float dy = py[i] - cy;
            const float s  = __fsqrt_rn(__fadd_rn(__fmul_rn(dx, dx),
                                                  __fmul_rn(dy, dy)));
            const bool lt = s < sbest[i];     // strict: ties keep earlier k
            sbest[i] = lt ? s : sbest[i];
            bidx[i]  = lt ? (k + 1) : bidx[i];
        }
    }

    *reinterpret_cast<int4*>(out + base) =
        make_int4(bidx[0], bidx[1], bidx[2], bidx[3]);
}

extern "C" void kernel_launch(void* const* d_in, const int* in_sizes, int n_in,
                              void* d_out, int out_size, void* d_ws, size_t ws_size,
                              hipStream_t stream) {
    const float* reg = (const float*)d_in[0];   // instance_regressions (2,H,W)
    const float* cc  = (const float*)d_in[1];   // center_coords (K,2)
    int* out = (int*)d_out;                     // (H,W) int32

    const int threads_total = (H_ * W_) / 4;    // 4 pixels per thread
    inst_map_kernel<<<threads_total / 256, 256, 0, stream>>>(reg, cc, out);
}

// Round 2
// 86.040 us; speedup vs baseline: 1.4104x; 1.4104x over previous
//
#include <hip/hip_runtime.h>

// CreateInstMap: out[r,c] = 1 + argmin_k sqrt((px-cx[k])^2 + (py-cy[k])^2)
//   px = (c+1) - reg[0,r,c], py = (r+1) - reg[1,r,c]; cy=cc[k,0], cx=cc[k,1].
//
// Strategy (round 2):
//  * argmin on d^2 (exact __fmul_rn/__fadd_rn, identical to ref's pre-sqrt
//    value) instead of the ~15-instr __fsqrt_rn expansion. Mismatch vs the
//    reference can only occur when an earlier-index center has larger d^2
//    whose rounded sqrt equals the min's — such pairs satisfy
//    (d2_old - d2_new) <= ~2^-21 * d2 and always appear as a best-replacement
//    step in the scan. We flag that window (2^-19, 4x margin) and fall back
//    per-lane to the exact __fsqrt_rn loop (probability ~1e-6).
//  * per-tile center pruning: all pred points of a 32x32 tile lie within
//    measured radius R of the tile anchor t, so center k is irrelevant unless
//    d(k,t) <= min_j d(j,t) + 2R (+4.0 slack >> all fp error, values O(2000),
//    errors O(1e-3)). Surviving candidates (expected ~15-20 of 64) are
//    compacted in original-k order into LDS.

#define H_ 1024
#define W_ 2048
#define K_ 64
#define TR_ 32
#define TC_ 32
#define HAZC 1.9073486e-6f   // 2^-19: sqrt-collision window with 4x margin

__global__ __launch_bounds__(256) void inst_map_kernel(
    const float* __restrict__ reg,   // (2, H, W) float32
    const float* __restrict__ cc,    // (K, 2)    float32, [k] = (cy, cx)
    int* __restrict__ out)           // (H, W)    int32
{
    __shared__ float4 cand[K_ + 1];  // (cx, cy, (k+1) as int bits, 0) + pad slot
    __shared__ float  wmaxd2[4];     // per-wave max |pred - anchor|^2
    __shared__ int    ncand_s;

    const int tid = threadIdx.x;
    const int tr0 = blockIdx.y * TR_;
    const int tc0 = blockIdx.x * TC_;
    const int r = tr0 + (tid >> 3);            // 32 rows
    const int c = tc0 + ((tid & 7) << 2);      // 8 threads x 4 px per row
    const int base = r * W_ + c;

    const float4 rx = *reinterpret_cast<const float4*>(reg + base);
    const float4 ry = *reinterpret_cast<const float4*>(reg + H_ * W_ + base);

    // tile anchor in pred-coordinate space (pixel x = c+1 spans [tc0+1, tc0+32])
    const float tcx = (float)tc0 + 16.5f;
    const float tcy = (float)tr0 + 16.5f;

    float px[4], py[4];
    const float yf = (float)(r + 1);
    px[0] = (float)(c + 1) - rx.x;
    px[1] = (float)(c + 2) - rx.y;
    px[2] = (float)(c + 3) - rx.z;
    px[3] = (float)(c + 4) - rx.w;
    py[0] = yf - ry.x;
    py[1] = yf - ry.y;
    py[2] = yf - ry.z;
    py[3] = yf - ry.w;

    // ---- measure tile radius: max over tile of |pred - anchor| ----
    float m = 0.0f;
    #pragma unroll
    for (int i = 0; i < 4; ++i) {
        const float ax = px[i] - tcx, ay = py[i] - tcy;
        m = fmaxf(m, ax * ax + ay * ay);
    }
    #pragma unroll
    for (int s = 1; s < 64; s <<= 1)
        m = fmaxf(m, __shfl_xor(m, s, 64));
    if ((tid & 63) == 0) wmaxd2[tid >> 6] = m;
    __syncthreads();

    // ---- wave 0: prune + compact candidate centers (original-k order) ----
    if (tid < K_) {
        const float R2 = fmaxf(fmaxf(wmaxd2[0], wmaxd2[1]),
                               fmaxf(wmaxd2[2], wmaxd2[3]));
        const float Rt = sqrtf(R2);
        const float cyk = cc[2 * tid];
        const float cxk = cc[2 * tid + 1];
        const float ddx = cxk - tcx, ddy = cyk - tcy;
        const float d = sqrtf(ddx * ddx + ddy * ddy);
        float dmin = d;
        #pragma unroll
        for (int s = 1; s < 64; s <<= 1)
            dmin = fminf(dmin, __shfl_xor(dmin, s, 64));
        // k can win for some pixel only if d(k,t) <= dmin + 2R (+slack)
        const bool keep = d <= dmin + 2.0f * Rt + 4.0f;
        const unsigned long long mask = __ballot(keep);
        if (keep) {
            const int pos = (int)__popcll(mask & ((1ull << tid) - 1ull));
            cand[pos] = make_float4(cxk, cyk, __int_as_float(tid + 1), 0.0f);
        }
        if (tid == 0) {
            const int n = (int)__popcll(mask);
            ncand_s = n;
            cand[n] = make_float4(0.0f, 0.0f, __int_as_float(1), 0.0f); // prefetch pad
        }
    }
    __syncthreads();

    const int ncand = ncand_s;

    // ---- main loop: exact-d^2 argmin with sqrt-collision hazard guard ----
    float best[4] = {INFINITY, INFINITY, INFINITY, INFINITY};
    int   bidx[4] = {1, 1, 1, 1};
    bool  haz = false;

    float4 cd = cand[0];
    for (int j = 0; j < ncand; ++j) {
        const float4 nx = cand[j + 1];           // one-ahead prefetch (pad slot safe)
        const float cxk = cd.x, cyk = cd.y;
        const int   kk  = __float_as_int(cd.z);
        #pragma unroll
        for (int i = 0; i < 4; ++i) {
            const float dx = px[i] - cxk;
            const float dy = py[i] - cyk;
            const float d2 = __fadd_rn(__fmul_rn(dx, dx), __fmul_rn(dy, dy));
            const bool lt = d2 < best[i];
            haz = haz || (lt && (best[i] - d2 <= __fmul_rn(d2, HAZC)));
            best[i] = lt ? d2 : best[i];
            bidx[i] = lt ? kk : bidx[i];
        }
        cd = nx;
    }

    // ---- rare exact fallback: replicate reference's sqrt compare bit-exactly ----
    if (haz) {
        float sb[4]  = {INFINITY, INFINITY, INFINITY, INFINITY};
        int   bi2[4] = {1, 1, 1, 1};
        for (int j = 0; j < ncand; ++j) {
            const float4 c2 = cand[j];
            const int kk = __float_as_int(c2.z);
            #pragma unroll
            for (int i = 0; i < 4; ++i) {
                const float dx = px[i] - c2.x;
                const float dy = py[i] - c2.y;
                const float s = __fsqrt_rn(__fadd_rn(__fmul_rn(dx, dx),
                                                     __fmul_rn(dy, dy)));
                if (s < sb[i]) { sb[i] = s; bi2[i] = kk; }
            }
        }
        #pragma unroll
        for (int i = 0; i < 4; ++i) bidx[i] = bi2[i];
    }

    *reinterpret_cast<int4*>(out + base) =
        make_int4(bidx[0], bidx[1], bidx[2], bidx[3]);
}

extern "C" void kernel_launch(void* const* d_in, const int* in_sizes, int n_in,
                              void* d_out, int out_size, void* d_ws, size_t ws_size,
                              hipStream_t stream) {
    const float* reg = (const float*)d_in[0];   // instance_regressions (2,H,W)
    const float* cc  = (const float*)d_in[1];   // center_coords (K,2)
    int* out = (int*)d_out;                     // (H,W) int32

    dim3 grid(W_ / TC_, H_ / TR_);              // (64, 32)
    inst_map_kernel<<<grid, 256, 0, stream>>>(reg, cc, out);
}

// Round 3
// 85.625 us; speedup vs baseline: 1.4172x; 1.0048x over previous
//
#include <hip/hip_runtime.h>

// CreateInstMap: out[r,c] = 1 + argmin_k sqrt((px-cx[k])^2 + (py-cy[k])^2)
//   px = (c+1) - reg[0,r,c], py = (r+1) - reg[1,r,c]; cy=cc[k,0], cx=cc[k,1].
//
// Round 3 structure:
//  * Per-WAVE center pruning (8x32-px strip, own LDS region, no cross-wave
//    serialization): keep k iff d(k,anchor) <= dmin + 2R + 4, R measured from
//    the strip's actual pred points. Slack 4.0 >> all fp error (~1e-2).
//    Compaction preserves k-order => first-index tie semantics.
//  * Main loop: argmin on g = ck - 2px'cx' - 2py'cy'  (= d^2 - |p'|^2, per-
//    pixel constant dropped), wave-anchor-shifted coords keep |terms| <= ~2.4e6
//    so the 2-FMA chain has abs error <= ~0.6. Track best AND second-best.
//  * Exactness: if sec-best <= TAU (covers fma err ~1.2 + shift drift ~0.8 +
//    ref d2 rounding ~0.3 + sqrt-collision window ~1.5; TAU=8 is 2x margin),
//    the wave re-runs the bit-exact reference math (__fmul_rn/__fadd_rn/
//    __fsqrt_rn, strict <, exact cc reloaded from global) over survivors.
//    Gaps are typically ~1e4 => fallback ~5-10% of waves.

#define H_ 1024
#define W_ 2048
#define K_ 64
#define TAU 8.0f

__global__ __launch_bounds__(256) void inst_map_kernel(
    const float* __restrict__ reg,   // (2, H, W) float32
    const float* __restrict__ cc,    // (K, 2)    float32, [k] = (cy, cx)
    int* __restrict__ out)           // (H, W)    int32
{
    __shared__ float4 cand[4][K_ + 1];  // per wave: (cx', cy', ck, kbits) + pad

    const int tid  = threadIdx.x;
    const int w    = tid >> 6;              // wave id
    const int lane = tid & 63;
    const int tr0  = blockIdx.y * 32;
    const int tc0  = blockIdx.x * 32;
    const int r    = tr0 + w * 8 + (lane >> 3);   // wave strip: 8 rows
    const int c    = tc0 + ((lane & 7) << 2);     // x 32 cols, 4 px/thread
    const int base = r * W_ + c;

    const float4 rx = *reinterpret_cast<const float4*>(reg + base);
    const float4 ry = *reinterpret_cast<const float4*>(reg + H_ * W_ + base);

    // strip anchor in pred space (pixel coords are 1-based)
    const float ax = (float)tc0 + 16.5f;
    const float ay = (float)(tr0 + w * 8) + 4.5f;

    // exact reference pred values (kept for the exact fallback)
    float px[4], py[4];
    const float yf = (float)(r + 1);
    px[0] = (float)(c + 1) - rx.x;  py[0] = yf - ry.x;
    px[1] = (float)(c + 2) - rx.y;  py[1] = yf - ry.y;
    px[2] = (float)(c + 3) - rx.z;  py[2] = yf - ry.z;
    px[3] = (float)(c + 4) - rx.w;  py[3] = yf - ry.w;

    // shifted coords + main-loop coefficients; strip radius
    float pxn[4], pyn[4];
    float m = 0.0f;
    #pragma unroll
    for (int i = 0; i < 4; ++i) {
        const float sx = px[i] - ax, sy = py[i] - ay;
        pxn[i] = -2.0f * sx;
        pyn[i] = -2.0f * sy;
        m = fmaxf(m, sx * sx + sy * sy);
    }
    #pragma unroll
    for (int s = 1; s < 64; s <<= 1)
        m = fmaxf(m, __shfl_xor(m, s, 64));
    const float Rt = sqrtf(m);

    // ---- per-wave prune: 1 center per lane, compact in k-order ----
    const float cyk = cc[2 * lane];
    const float cxk = cc[2 * lane + 1];
    const float sx = cxk - ax, sy = cyk - ay;
    const float ck = sx * sx + sy * sy;
    const float d  = sqrtf(ck);
    float dmin = d;
    #pragma unroll
    for (int s = 1; s < 64; s <<= 1)
        dmin = fminf(dmin, __shfl_xor(dmin, s, 64));
    const bool keep = d <= dmin + 2.0f * Rt + 4.0f;
    const unsigned long long mask = __ballot(keep);
    const int ncand = (int)__popcll(mask);
    if (keep) {
        const int pos = (int)__popcll(mask & ((1ull << lane) - 1ull));
        cand[w][pos] = make_float4(sx, sy, ck, __int_as_float(lane + 1));
    }
    if (lane == 0)   // pad slot: g evaluates to +inf, never wins
        cand[w][ncand] = make_float4(0.0f, 0.0f, INFINITY, __int_as_float(1));
    __syncthreads();

    // ---- main loop: 2 FMA per pixel-candidate, best + second-best ----
    float best[4] = {INFINITY, INFINITY, INFINITY, INFINITY};
    float sec[4]  = {INFINITY, INFINITY, INFINITY, INFINITY};
    int   bidx[4] = {1, 1, 1, 1};

    float4 cd = cand[w][0];
    for (int j = 0; j < ncand; ++j) {
        const float4 nx = cand[w][j + 1];      // one-ahead prefetch (pad-safe)
        #pragma unroll
        for (int i = 0; i < 4; ++i) {
            const float g = __fmaf_rn(pxn[i], cd.x,
                            __fmaf_rn(pyn[i], cd.y, cd.z));
            const bool lt = g < best[i];
            const float mn = fminf(sec[i], g);
            sec[i]  = lt ? best[i] : mn;
            best[i] = lt ? g : best[i];
            bidx[i] = lt ? __float_as_int(cd.w) : bidx[i];
        }
        cd = nx;
    }

    // ---- rare exact fallback: bit-exact reference math over survivors ----
    bool haz = false;
    #pragma unroll
    for (int i = 0; i < 4; ++i)
        haz = haz | (sec[i] - best[i] <= TAU);
    if (__any(haz)) {
        float sb[4]  = {INFINITY, INFINITY, INFINITY, INFINITY};
        int   bi2[4] = {1, 1, 1, 1};
        for (int j = 0; j < ncand; ++j) {
            const int kk = __float_as_int(cand[w][j].w);
            const float ecy = cc[2 * (kk - 1)];       // exact coords
            const float ecx = cc[2 * (kk - 1) + 1];
            #pragma unroll
            for (int i = 0; i < 4; ++i) {
                const float dx = px[i] - ecx;
                const float dy = py[i] - ecy;
                const float s2 = __fsqrt_rn(__fadd_rn(__fmul_rn(dx, dx),
                                                      __fmul_rn(dy, dy)));
                const bool lt = s2 < sb[i];           // strict: first-index ties
                sb[i]  = lt ? s2 : sb[i];
                bi2[i] = lt ? kk : bi2[i];
            }
        }
        #pragma unroll
        for (int i = 0; i < 4; ++i) bidx[i] = bi2[i];
    }

    *reinterpret_cast<int4*>(out + base) =
        make_int4(bidx[0], bidx[1], bidx[2], bidx[3]);
}

extern "C" void kernel_launch(void* const* d_in, const int* in_sizes, int n_in,
                              void* d_out, int out_size, void* d_ws, size_t ws_size,
                              hipStream_t stream) {
    const float* reg = (const float*)d_in[0];   // instance_regressions (2,H,W)
    const float* cc  = (const float*)d_in[1];   // center_coords (K,2)
    int* out = (int*)d_out;                     // (H,W) int32

    dim3 grid(W_ / 32, H_ / 32);                // (64, 32) = 2048 blocks
    inst_map_kernel<<<grid, 256, 0, stream>>>(reg, cc, out);
}